// Round 1
// baseline (218.897 us; speedup 1.0000x reference)
//
#include <hip/hip_runtime.h>
#include <hip/hip_bf16.h>
#include <stdint.h>
#include <type_traits>

// ---------------------------------------------------------------------------
// Fused attention: out = softmax((x Wq^T)(x Wk^T)^T / sqrt(d)) (x Wv^T)
// B=4, S=2048, D=1024, fp32 in/out, bf16 MFMA internal compute.
//
// Pipeline:
//   1. cast x, Wq, Wk, Wv -> bf16 in ws
//   2. NT GEMM (m97-style 128x128 tile): Qb = xb Wq^T, Kb = xb Wk^T,
//      Vt[b][e][s] = (xb Wv^T)^T   (transposed store so PV is NT-form)
//   3. NT GEMM: S[b][q][k] = Qb Kb^T * (1/32), bf16
//   4. row softmax in-place on S (fp32 math)
//   5. NT GEMM: out[b][q][e] = P Vt^T, fp32 store
// ---------------------------------------------------------------------------

typedef __attribute__((ext_vector_type(8))) short short8;
typedef __attribute__((ext_vector_type(4))) float f32x4;

#define GL_G(p) ((const __attribute__((address_space(1))) void*)(p))
#define GL_L(p) ((__attribute__((address_space(3))) void*)(p))

__device__ __forceinline__ float bf2f(unsigned short u) {
  union { float f; uint32_t i; } c; c.i = ((uint32_t)u) << 16; return c.f;
}
__device__ __forceinline__ unsigned short f2bf(float f) {
  __hip_bfloat16 h = __float2bfloat16(f);
  return *reinterpret_cast<unsigned short*>(&h);
}

// ---------------- cast fp32 -> bf16 (vectorized) ----------------
__global__ __launch_bounds__(256) void cast_f32_to_bf16(
    const float* __restrict__ in, unsigned short* __restrict__ out, long n) {
  long tid = (long)blockIdx.x * blockDim.x + threadIdx.x;
  long stride = (long)gridDim.x * blockDim.x;
  for (long j = tid * 8; j < n; j += stride * 8) {
    float4 a = *(const float4*)(in + j);
    float4 b = *(const float4*)(in + j + 4);
    uint4 pk;
    pk.x = (uint32_t)f2bf(a.x) | ((uint32_t)f2bf(a.y) << 16);
    pk.y = (uint32_t)f2bf(a.z) | ((uint32_t)f2bf(a.w) << 16);
    pk.z = (uint32_t)f2bf(b.x) | ((uint32_t)f2bf(b.y) << 16);
    pk.w = (uint32_t)f2bf(b.z) | ((uint32_t)f2bf(b.w) << 16);
    *(uint4*)(out + j) = pk;
  }
}

// ---------------- generic NT GEMM: C[m,n] = scale * sum_k A[m,k] B[n,k] ----
// A: [M x K] bf16 row-major (ldA), B: [N x K] bf16 row-major (ldB)
// OUT_T: float or ushort(bf16). TRANS: store C[n*ldC + m] instead.
// 128x128 tile, BK=64, 256 threads (4 waves, 2x2), 16x16x32 bf16 MFMA.
// Requires M%128==0, N%128==0, K%64==0.
template <typename OUT_T, bool TRANS>
__global__ __launch_bounds__(256) void gemm_nt(
    const unsigned short* __restrict__ A, const unsigned short* __restrict__ B,
    OUT_T* __restrict__ C, int K, int ldA, int ldB, int ldC,
    long strideA, long strideB, long strideC, float scale) {
  __shared__ unsigned short As[128 * 64];
  __shared__ unsigned short Bs[128 * 64];

  const int tid = threadIdx.x;
  const int wid = tid >> 6;
  const int lane = tid & 63;
  const int wr = wid >> 1;        // wave row (0..1)
  const int wc = wid & 1;         // wave col (0..1)
  const int fr = lane & 15;       // fragment row/col within 16
  const int kg = (lane >> 4) * 8; // k-offset of this lane's 8 contiguous elems

  const int z = blockIdx.z;
  A += (long)z * strideA;
  B += (long)z * strideB;
  C += (long)z * strideC;

  const int brow = blockIdx.x * 128;
  const int bcol = blockIdx.y * 128;

  // staging geometry: tile is 128 rows x 128 bytes (64 bf16); 4 rounds of
  // 256 threads x 16B. linear byte offset = r*4096 + tid*16.
  int srow[4], scolb[4];
#pragma unroll
  for (int r = 0; r < 4; ++r) {
    int lin = r * 4096 + tid * 16;
    srow[r] = lin >> 7;
    scolb[r] = lin & 127;
  }

  f32x4 acc[4][4];
#pragma unroll
  for (int m = 0; m < 4; ++m)
#pragma unroll
    for (int n = 0; n < 4; ++n) acc[m][n] = (f32x4){0.f, 0.f, 0.f, 0.f};

  const char* aBase = (const char*)A;
  const char* bBase = (const char*)B;

  for (int kt = 0; kt < K; kt += 64) {
#pragma unroll
    for (int r = 0; r < 4; ++r) {
      const char* ga =
          aBase + ((long)(brow + srow[r]) * ldA + kt) * 2 + scolb[r];
      const char* gb =
          bBase + ((long)(bcol + srow[r]) * ldB + kt) * 2 + scolb[r];
      __builtin_amdgcn_global_load_lds(GL_G(ga),
                                       GL_L((char*)As + r * 4096 + wid * 1024),
                                       16, 0, 0);
      __builtin_amdgcn_global_load_lds(GL_G(gb),
                                       GL_L((char*)Bs + r * 4096 + wid * 1024),
                                       16, 0, 0);
    }
    __syncthreads();
#pragma unroll
    for (int ks = 0; ks < 2; ++ks) {
      short8 af[4], bfr[4];
#pragma unroll
      for (int m = 0; m < 4; ++m)
        af[m] = *(const short8*)&As[(wr * 64 + m * 16 + fr) * 64 + ks * 32 + kg];
#pragma unroll
      for (int n = 0; n < 4; ++n)
        bfr[n] = *(const short8*)&Bs[(wc * 64 + n * 16 + fr) * 64 + ks * 32 + kg];
#pragma unroll
      for (int m = 0; m < 4; ++m)
#pragma unroll
        for (int n = 0; n < 4; ++n)
          acc[m][n] = __builtin_amdgcn_mfma_f32_16x16x32_bf16(
              af[m], bfr[n], acc[m][n], 0, 0, 0);
    }
    __syncthreads();
  }

  // epilogue: C/D layout col = lane&15, row = (lane>>4)*4 + r
#pragma unroll
  for (int m = 0; m < 4; ++m) {
    const int rowg0 = brow + wr * 64 + m * 16 + (lane >> 4) * 4;
#pragma unroll
    for (int n = 0; n < 4; ++n) {
      const int colg = bcol + wc * 64 + n * 16 + fr;
      f32x4 v = acc[m][n];
      if constexpr (TRANS) {
        // store C[colg][rowg0..rowg0+3] — 4 contiguous bf16 (8B)
        ushort4 pk;
        pk.x = f2bf(v[0] * scale);
        pk.y = f2bf(v[1] * scale);
        pk.z = f2bf(v[2] * scale);
        pk.w = f2bf(v[3] * scale);
        *(ushort4*)((unsigned short*)C + (long)colg * ldC + rowg0) = pk;
      } else {
#pragma unroll
        for (int r = 0; r < 4; ++r) {
          float val = v[r] * scale;
          if constexpr (std::is_same<OUT_T, float>::value)
            C[(long)(rowg0 + r) * ldC + colg] = val;
          else
            C[(long)(rowg0 + r) * ldC + colg] = f2bf(val);
        }
      }
    }
  }
}

// ---------------- row softmax in-place on bf16 [rows x 2048] ----------------
__global__ __launch_bounds__(256) void softmax_inplace(
    unsigned short* __restrict__ S) {
  unsigned short* row = S + (size_t)blockIdx.x * 2048;
  const int tid = threadIdx.x;
  const int wid = tid >> 6;
  const int lane = tid & 63;

  uint4 raw = *(const uint4*)(row + tid * 8);
  float v[8];
  v[0] = bf2f(raw.x & 0xffff); v[1] = bf2f(raw.x >> 16);
  v[2] = bf2f(raw.y & 0xffff); v[3] = bf2f(raw.y >> 16);
  v[4] = bf2f(raw.z & 0xffff); v[5] = bf2f(raw.z >> 16);
  v[6] = bf2f(raw.w & 0xffff); v[7] = bf2f(raw.w >> 16);

  float mx = v[0];
#pragma unroll
  for (int i = 1; i < 8; ++i) mx = fmaxf(mx, v[i]);
#pragma unroll
  for (int off = 32; off; off >>= 1) mx = fmaxf(mx, __shfl_xor(mx, off));

  __shared__ float sred[8];
  if (lane == 0) sred[wid] = mx;
  __syncthreads();
  mx = fmaxf(fmaxf(sred[0], sred[1]), fmaxf(sred[2], sred[3]));

  float e[8];
  float s = 0.f;
#pragma unroll
  for (int i = 0; i < 8; ++i) {
    e[i] = __expf(v[i] - mx);
    s += e[i];
  }
#pragma unroll
  for (int off = 32; off; off >>= 1) s += __shfl_xor(s, off);
  if (lane == 0) sred[4 + wid] = s;
  __syncthreads();
  s = (sred[4] + sred[5]) + (sred[6] + sred[7]);
  float inv = 1.0f / s;

  uint4 pk;
  pk.x = (uint32_t)f2bf(e[0] * inv) | ((uint32_t)f2bf(e[1] * inv) << 16);
  pk.y = (uint32_t)f2bf(e[2] * inv) | ((uint32_t)f2bf(e[3] * inv) << 16);
  pk.z = (uint32_t)f2bf(e[4] * inv) | ((uint32_t)f2bf(e[5] * inv) << 16);
  pk.w = (uint32_t)f2bf(e[6] * inv) | ((uint32_t)f2bf(e[7] * inv) << 16);
  *(uint4*)(row + tid * 8) = pk;
}

// ---------------------------------------------------------------------------
extern "C" void kernel_launch(void* const* d_in, const int* in_sizes, int n_in,
                              void* d_out, int out_size, void* d_ws,
                              size_t ws_size, hipStream_t stream) {
  const float* x = (const float*)d_in[0];
  const float* Wq = (const float*)d_in[1];
  const float* Wk = (const float*)d_in[2];
  const float* Wv = (const float*)d_in[3];
  float* out = (float*)d_out;

  const long XE = 4L * 2048 * 1024;  // 8,388,608 elems
  const long WE = 1024L * 1024;      // 1,048,576 elems
  const long SE = 4L * 2048 * 2048;  // 16,777,216 elems

  unsigned short* xb = (unsigned short*)d_ws;
  unsigned short* Wqb = xb + XE;
  unsigned short* Wkb = Wqb + WE;
  unsigned short* Wvb = Wkb + WE;
  unsigned short* Qb = Wvb + WE;
  unsigned short* Kb = Qb + XE;
  unsigned short* Vtb = Kb + XE;   // [b][e][s] (transposed V)
  unsigned short* Sb = Vtb + XE;   // [b][q][k] scores -> probs
  // total: (4*XE + 3*WE + SE) * 2 = 106,954,752 bytes
  if (ws_size < (size_t)(4 * XE + 3 * WE + SE) * 2) return;  // loud failure

  cast_f32_to_bf16<<<1024, 256, 0, stream>>>(x, xb, XE);
  cast_f32_to_bf16<<<256, 256, 0, stream>>>(Wq, Wqb, WE);
  cast_f32_to_bf16<<<256, 256, 0, stream>>>(Wk, Wkb, WE);
  cast_f32_to_bf16<<<256, 256, 0, stream>>>(Wv, Wvb, WE);

  // Q = xb Wq^T  [8192 x 1024]
  gemm_nt<unsigned short, false><<<dim3(64, 8, 1), 256, 0, stream>>>(
      xb, Wqb, Qb, 1024, 1024, 1024, 1024, 0, 0, 0, 1.0f);
  // K = xb Wk^T  [8192 x 1024]
  gemm_nt<unsigned short, false><<<dim3(64, 8, 1), 256, 0, stream>>>(
      xb, Wkb, Kb, 1024, 1024, 1024, 1024, 0, 0, 0, 1.0f);
  // Vt[b][e][s] = (xb Wv^T)^T, per batch
  gemm_nt<unsigned short, true><<<dim3(16, 8, 4), 256, 0, stream>>>(
      xb, Wvb, Vtb, 1024, 1024, 1024, 2048, 2048L * 1024, 0, 1024L * 2048,
      1.0f);
  // S[b][q][k] = Qb Kb^T / 32, per batch
  gemm_nt<unsigned short, false><<<dim3(16, 16, 4), 256, 0, stream>>>(
      Qb, Kb, Sb, 1024, 1024, 1024, 2048, 2048L * 1024, 2048L * 1024,
      2048L * 2048, 0.03125f);
  // softmax rows (4*2048 rows of 2048)
  softmax_inplace<<<8192, 256, 0, stream>>>(Sb);
  // out[b][q][e] = P Vt^T, per batch, fp32
  gemm_nt<float, false><<<dim3(16, 8, 4), 256, 0, stream>>>(
      Sb, Vtb, out, 2048, 2048, 2048, 1024, 2048L * 2048, 1024L * 2048,
      2048L * 1024, 1.0f);
}